// Round 1
// baseline (740.643 us; speedup 1.0000x reference)
//
#include <hip/hip_runtime.h>
#include <math.h>

#define NB 256
#define NV 32000
#define ND 1024
#define NT 64
#define TPB 512
#define NWAVE (TPB / 64)

// ---------------- fp32 GEMM: C[b][v] = sum_d A[b][d] * Bm[v][d] ----------------
__global__ __launch_bounds__(256) void gemm_f32(
    const float* __restrict__ A,   // hidden   [256][1024]
    const float* __restrict__ Bm,  // embedding[32000][1024]
    float* __restrict__ C)         // logits   [256][32000]
{
  __shared__ float As[32][128];
  __shared__ float Bs[32][128];
  const int t  = threadIdx.x;
  const int vv = blockIdx.x * 128;
  const int bb = blockIdx.y * 128;
  const int tx = t & 15, ty = t >> 4;
  float acc[8][8];
#pragma unroll
  for (int i = 0; i < 8; i++)
#pragma unroll
    for (int j = 0; j < 8; j++) acc[i][j] = 0.f;

  for (int k0 = 0; k0 < ND; k0 += 32) {
#pragma unroll
    for (int i = 0; i < 4; i++) {
      const int f  = i * 256 + t;
      const int r  = f >> 3;         // row within 128-tile
      const int k4 = (f & 7) << 2;   // k offset within 32-chunk
      const float4 av = *(const float4*)(A + (size_t)(bb + r) * ND + k0 + k4);
      As[k4 + 0][r] = av.x; As[k4 + 1][r] = av.y;
      As[k4 + 2][r] = av.z; As[k4 + 3][r] = av.w;
      const float4 bv = *(const float4*)(Bm + (size_t)(vv + r) * ND + k0 + k4);
      Bs[k4 + 0][r] = bv.x; Bs[k4 + 1][r] = bv.y;
      Bs[k4 + 2][r] = bv.z; Bs[k4 + 3][r] = bv.w;
    }
    __syncthreads();
#pragma unroll
    for (int k = 0; k < 32; k++) {
      float a0[8], b0[8];
      *(float4*)&a0[0] = *(const float4*)&As[k][ty * 8];
      *(float4*)&a0[4] = *(const float4*)&As[k][ty * 8 + 4];
      *(float4*)&b0[0] = *(const float4*)&Bs[k][tx * 8];
      *(float4*)&b0[4] = *(const float4*)&Bs[k][tx * 8 + 4];
#pragma unroll
      for (int i = 0; i < 8; i++)
#pragma unroll
        for (int j = 0; j < 8; j++)
          acc[i][j] = fmaf(a0[i], b0[j], acc[i][j]);
    }
    __syncthreads();
  }
#pragma unroll
  for (int i = 0; i < 8; i++) {
    float* dst = C + (size_t)(bb + ty * 8 + i) * NV + vv + tx * 8;
    *(float4*)(dst)     = make_float4(acc[i][0], acc[i][1], acc[i][2], acc[i][3]);
    *(float4*)(dst + 4) = make_float4(acc[i][4], acc[i][5], acc[i][6], acc[i][7]);
  }
}

// ---------------- per-row softmax + penalties + top-k/top-p filter ----------------
// One block per row. Row data lives in buf (d_out) and is transformed in place:
// logits -> x = (logits - pen)/T -> e = exp(x - M) -> p = e/Z -> filtered p.
// Every strided pass touches only the thread's own elements; cross-thread data
// only flows through deterministic shfl/LDS tree reductions.
__global__ __launch_bounds__(TPB) void sample_rows(
    const int* __restrict__ toks,    // [256][64]
    const float* __restrict__ pres,  // [256]
    const float* __restrict__ freq,  // [256]
    const float* __restrict__ temp,  // [256]
    const float* __restrict__ topp_a,// [256]
    const int* __restrict__ topk_a,  // [256]
    float* __restrict__ buf)         // [256][32000]
{
  const int b    = blockIdx.x;
  const int tid  = threadIdx.x;
  const int lane = tid & 63, wav = tid >> 6;
  float* row = buf + (size_t)b * NV;

  __shared__ int    s_tok[NT];
  __shared__ float  s_f[NWAVE];
  __shared__ double s_d[NWAVE];
  __shared__ int    s_c[NWAVE][16];
  __shared__ double s_s[NWAVE][16];
  __shared__ int    s_rank[TPB];

  const float  invT = 1.0f / temp[b];
  const float  fpen = freq[b];
  const float  ppen = pres[b];
  const double topp = (double)topp_a[b];
  const int    ktop = topk_a[b];

  if (tid < NT) s_tok[tid] = toks[b * NT + tid];
  __syncthreads();

  // ---- P1: x = logit * invT (pre-penalty), block max (valid upper bound) ----
  float lmax = -3.4e38f;
  for (int v = tid; v < NV; v += TPB) {
    float x = row[v] * invT;
    row[v] = x;
    lmax = fmaxf(lmax, x);
  }
#pragma unroll
  for (int o = 32; o; o >>= 1) lmax = fmaxf(lmax, __shfl_down(lmax, o));
  if (lane == 0) s_f[wav] = lmax;
  __syncthreads();   // also drains the row[] writes above (vmcnt before barrier)
  float M = s_f[0];
#pragma unroll
  for (int w = 1; w < NWAVE; w++) M = fmaxf(M, s_f[w]);

  // ---- penalty fixup: first occurrence of each token applies full count ----
  if (tid < NT) {
    const int tk = s_tok[tid];
    bool first = true;
    int cnt = 0;
    for (int j = 0; j < NT; j++) {
      if (s_tok[j] == tk) {
        if (j < tid) first = false;
        cnt++;
      }
    }
    if (first) row[tk] -= (fpen * (float)cnt + ppen) * invT;
  }
  __threadfence_block();
  __syncthreads();

  // ---- P2: e = exp(x - M), Z (double) ----
  double zl = 0.0;
  for (int v = tid; v < NV; v += TPB) {
    float e = expf(row[v] - M);
    row[v] = e;
    zl += (double)e;
  }
#pragma unroll
  for (int o = 32; o; o >>= 1) zl += __shfl_down(zl, o);
  if (lane == 0) s_d[wav] = zl;
  __syncthreads();
  double Z = 0.0;
#pragma unroll
  for (int w = 0; w < NWAVE; w++) Z += s_d[w];
  const float invZ = (float)(1.0 / Z);

  // ---- P3: p = e * invZ, stats at threshold 0 (count/sum of p > 0) ----
  int c0 = 0; double s0 = 0.0;
  for (int v = tid; v < NV; v += TPB) {
    float p = row[v] * invZ;
    row[v] = p;
    if (__float_as_uint(p) > 0u) { c0++; s0 += (double)p; }
  }
#pragma unroll
  for (int o = 32; o; o >>= 1) { c0 += __shfl_down(c0, o); s0 += __shfl_down(s0, o); }
  __syncthreads();
  if (lane == 0) { s_c[wav][0] = c0; s_s[wav][0] = s0; }
  __syncthreads();
  int Clo = 0; double Slo = 0.0;
#pragma unroll
  for (int w = 0; w < NWAVE; w++) { Clo += s_c[w][0]; Slo += s_s[w][0]; }

  // ---- 16-way bisection over float bit space for cutoff u* ----
  // Invariant: A(hi) true, A(lo) false, where A(u) = (C(u) < ktop && S(u) <= topp),
  // C/S = count/sum of p with bits(p) > u.  (Chi,Shi)/(Clo,Slo) track endpoint stats.
  unsigned lo = 0u, hi = 0x3F800000u;  // (0, 1.0]
  int Chi = 0; double Shi = 0.0;

  while (hi - lo > 1u) {
    const unsigned step = ((hi - lo) + 15u) >> 4;
    unsigned u[15];
#pragma unroll
    for (int i = 0; i < 15; i++) {
      unsigned ui = lo + (unsigned)(i + 1) * step;
      u[i] = (ui > hi) ? hi : ui;
    }
    int cnt[15]; float sum[15];
#pragma unroll
    for (int i = 0; i < 15; i++) { cnt[i] = 0; sum[i] = 0.f; }
    for (int v = tid; v < NV; v += TPB) {
      const float p = row[v];
      const unsigned key = __float_as_uint(p);
#pragma unroll
      for (int i = 0; i < 15; i++) {
        if (key > u[i]) { cnt[i]++; sum[i] += p; }
      }
    }
    __syncthreads();  // protect s_c/s_s readers of previous iteration
#pragma unroll
    for (int i = 0; i < 15; i++) {
      int c = cnt[i]; double sm = (double)sum[i];
#pragma unroll
      for (int o = 32; o; o >>= 1) { c += __shfl_down(c, o); sm += __shfl_down(sm, o); }
      if (lane == 0) { s_c[wav][i] = c; s_s[wav][i] = sm; }
    }
    __syncthreads();
    // uniform decision on all threads
    int sel = -1;
    for (int i = 0; i < 15; i++) {
      int c = 0; double sm = 0.0;
#pragma unroll
      for (int w = 0; w < NWAVE; w++) { c += s_c[w][i]; sm += s_s[w][i]; }
      const bool At = (c < ktop) && (sm <= topp);
      if (At) { sel = i; Chi = c; Shi = sm; hi = u[i]; break; }
      if (u[i] < hi) { lo = u[i]; Clo = c; Slo = sm; }
    }
    (void)sel;
  }

  // ---- cutoff resolved: u* = hi ----
  const unsigned ustar = hi;
  const int c_eq = Clo - Chi;                    // # elements with bits(p) == u*
  int m = c_eq;                                  // # of those kept (index order)
  {
    const int lim = ktop - Chi;
    if (lim < m) m = lim;
    const double tcut = (double)__uint_as_float(ustar);
    double rem = topp - Shi;
    if (rem < 0.0) rem = 0.0;
    const double Rd = floor(rem / tcut) + 1.0;   // # ranks r with Shi + r*t <= topp
    if (Rd < (double)m) m = (int)Rd;
  }
  if (m < 1) m = 1;  // A(u*) true guarantees rank 0 is kept

  if (m == c_eq) {
    // fast path: keep everything with bits >= u*
    for (int v = tid; v < NV; v += TPB) {
      const float p = row[v];
      row[v] = (__float_as_uint(p) >= ustar) ? p : 0.0f;
    }
  } else {
    // rare path: index-ordered tie ranking via contiguous chunks + prefix scan
    const int CH = (NV + TPB - 1) / TPB;
    int base = tid * CH; if (base > NV) base = NV;
    int end = base + CH; if (end > NV) end = NV;
    int myc = 0;
    for (int v = base; v < end; v++) myc += (__float_as_uint(row[v]) == ustar);
    s_rank[tid] = myc;
    __syncthreads();
    if (tid == 0) {
      int run = 0;
      for (int j = 0; j < TPB; j++) { int c = s_rank[j]; s_rank[j] = run; run += c; }
    }
    __syncthreads();
    int r = s_rank[tid];
    for (int v = base; v < end; v++) {
      const float p = row[v];
      const unsigned key = __float_as_uint(p);
      bool kept;
      if (key > ustar) kept = true;
      else if (key == ustar) { kept = (r < m); r++; }
      else kept = false;
      row[v] = kept ? p : 0.0f;
    }
  }
}

extern "C" void kernel_launch(void* const* d_in, const int* in_sizes, int n_in,
                              void* d_out, int out_size, void* d_ws, size_t ws_size,
                              hipStream_t stream) {
  (void)in_sizes; (void)n_in; (void)out_size; (void)d_ws; (void)ws_size;
  const float* hidden = (const float*)d_in[0];
  const float* emb    = (const float*)d_in[1];
  const int*   toks   = (const int*)d_in[2];
  const float* pres   = (const float*)d_in[3];
  const float* freq   = (const float*)d_in[4];
  const float* temp   = (const float*)d_in[5];
  const float* topp   = (const float*)d_in[6];
  const int*   topk   = (const int*)d_in[7];
  float* out = (float*)d_out;

  dim3 ggrid(NV / 128, NB / 128);
  gemm_f32<<<ggrid, 256, 0, stream>>>(hidden, emb, out);
  sample_rows<<<NB, TPB, 0, stream>>>(toks, pres, freq, temp, topp, topk, out);
}

// Round 2
// 677.750 us; speedup vs baseline: 1.0928x; 1.0928x over previous
//
#include <hip/hip_runtime.h>
#include <math.h>

#define NB 256
#define NV 32000
#define ND 1024
#define NT 64
#define TPB 1024
#define NWAVE (TPB / 64)   // 16
#define NBINS 2048
#define BSHIFT 19
#define BPT (NBINS / TPB)  // 2
#define CAP 1024

__device__ __forceinline__ unsigned mono_enc(float f) {
  unsigned u = __float_as_uint(f);
  return (u & 0x80000000u) ? ~u : (u | 0x80000000u);
}
__device__ __forceinline__ float mono_dec(unsigned u) {
  return (u & 0x80000000u) ? __uint_as_float(u & 0x7FFFFFFFu) : __uint_as_float(~u);
}

// ---------------- fp32 GEMM with fused epilogue: x = (A·B^T)*invT, row-max -> ws ----
__global__ __launch_bounds__(256) void gemm_f32(
    const float* __restrict__ A,    // hidden   [256][1024]
    const float* __restrict__ Bm,   // embedding[32000][1024]
    const float* __restrict__ temp, // [256]
    unsigned* __restrict__ ws_max,  // [256] monotone-uint row max (init 0)
    float* __restrict__ C)          // x = logits*invT  [256][32000]
{
  __shared__ float As[32][128];
  __shared__ float Bs[32][128];
  __shared__ float s_invT[128];
  const int t  = threadIdx.x;
  const int vv = blockIdx.x * 128;
  const int bb = blockIdx.y * 128;
  const int tx = t & 15, ty = t >> 4;
  if (t < 128) s_invT[t] = 1.0f / temp[bb + t];
  float acc[8][8];
#pragma unroll
  for (int i = 0; i < 8; i++)
#pragma unroll
    for (int j = 0; j < 8; j++) acc[i][j] = 0.f;

  for (int k0 = 0; k0 < ND; k0 += 32) {
#pragma unroll
    for (int i = 0; i < 4; i++) {
      const int f  = i * 256 + t;
      const int r  = f >> 3;
      const int k4 = (f & 7) << 2;
      const float4 av = *(const float4*)(A + (size_t)(bb + r) * ND + k0 + k4);
      As[k4 + 0][r] = av.x; As[k4 + 1][r] = av.y;
      As[k4 + 2][r] = av.z; As[k4 + 3][r] = av.w;
      const float4 bv = *(const float4*)(Bm + (size_t)(vv + r) * ND + k0 + k4);
      Bs[k4 + 0][r] = bv.x; Bs[k4 + 1][r] = bv.y;
      Bs[k4 + 2][r] = bv.z; Bs[k4 + 3][r] = bv.w;
    }
    __syncthreads();
#pragma unroll
    for (int k = 0; k < 32; k++) {
      float a0[8], b0[8];
      *(float4*)&a0[0] = *(const float4*)&As[k][ty * 8];
      *(float4*)&a0[4] = *(const float4*)&As[k][ty * 8 + 4];
      *(float4*)&b0[0] = *(const float4*)&Bs[k][tx * 8];
      *(float4*)&b0[4] = *(const float4*)&Bs[k][tx * 8 + 4];
#pragma unroll
      for (int i = 0; i < 8; i++)
#pragma unroll
        for (int j = 0; j < 8; j++)
          acc[i][j] = fmaf(a0[i], b0[j], acc[i][j]);
    }
    __syncthreads();
  }
#pragma unroll
  for (int i = 0; i < 8; i++) {
    const int r = ty * 8 + i;
    const float it = s_invT[r];
    float x[8]; float mx = -3.4e38f;
#pragma unroll
    for (int j = 0; j < 8; j++) { x[j] = acc[i][j] * it; mx = fmaxf(mx, x[j]); }
    float* dst = C + (size_t)(bb + r) * NV + vv + tx * 8;
    *(float4*)(dst)     = make_float4(x[0], x[1], x[2], x[3]);
    *(float4*)(dst + 4) = make_float4(x[4], x[5], x[6], x[7]);
#pragma unroll
    for (int off = 1; off < 16; off <<= 1) mx = fmaxf(mx, __shfl_xor(mx, off));
    if (tx == 0) atomicMax(&ws_max[bb + r], mono_enc(mx));
  }
}

// ---------------- per-row: exp -> Z -> penalties -> p -> histogram cutoff -> filter ----
__global__ __launch_bounds__(TPB) void sample_rows(
    const int* __restrict__ toks, const float* __restrict__ pres,
    const float* __restrict__ freq, const float* __restrict__ temp,
    const float* __restrict__ topp_a, const int* __restrict__ topk_a,
    const unsigned* __restrict__ ws_max, float* __restrict__ buf)
{
  const int b = blockIdx.x, tid = threadIdx.x;
  const int lane = tid & 63, wav = tid >> 6;
  float* row = buf + (size_t)b * NV;

  __shared__ int    s_tok[NT];
  __shared__ double s_d[NWAVE];
  __shared__ int    s_i[NWAVE];
  __shared__ int    hcnt[NBINS];
  __shared__ float  hsum[NBINS];
  __shared__ double hsumd[NBINS];
  __shared__ int    sc_c[TPB];
  __shared__ double sc_s[TPB];
  __shared__ int    s_c[NWAVE][16];
  __shared__ double s_s[NWAVE][16];
  __shared__ int    s_tc[16];
  __shared__ double s_ts[16];
  __shared__ unsigned cand_key[CAP];
  __shared__ int      cand_idx[CAP];
  __shared__ int    s_rank[TPB];
  __shared__ int    s_ncand;
  __shared__ int    s_bstar;
  __shared__ double s_dz;

  const float  invT = 1.0f / temp[b];
  const float  fpen = freq[b], ppen = pres[b];
  const double topp = (double)topp_a[b];
  const int    ktop = topk_a[b];
  const float  M    = mono_dec(ws_max[b]);

  if (tid < NT) s_tok[tid] = toks[b * NT + tid];
  for (int i = tid; i < NBINS; i += TPB) { hcnt[i] = 0; hsum[i] = 0.f; }
  if (tid == 0) { s_ncand = 0; s_bstar = 0; }
  __syncthreads();

  // token multiplicity + first-occurrence; snapshot x_tk before pass A overwrites
  float x_tk = 0.f; int cnt = 0; bool first = false; int tk = -1;
  if (tid < NT) {
    tk = s_tok[tid];
    first = true;
    for (int j = 0; j < NT; j++)
      if (s_tok[j] == tk) { if (j < tid) first = false; cnt++; }
    x_tk = row[tk];
  }
  __syncthreads();

  // ---- Pass A: e = exp(x - M), Z (double, deterministic) ----
  double zl = 0.0;
  for (int i = tid * 4; i < NV; i += TPB * 4) {
    float4 x4 = *(const float4*)(row + i);
    float4 e4;
    e4.x = expf(x4.x - M); e4.y = expf(x4.y - M);
    e4.z = expf(x4.z - M); e4.w = expf(x4.w - M);
    *(float4*)(row + i) = e4;
    zl += (double)e4.x + (double)e4.y + (double)e4.z + (double)e4.w;
  }
#pragma unroll
  for (int o = 32; o; o >>= 1) zl += __shfl_down(zl, o);
  if (lane == 0) s_d[wav] = zl;
  __syncthreads();
  double Z = 0.0;
#pragma unroll
  for (int w = 0; w < NWAVE; w++) Z += s_d[w];

  // ---- penalty fixup (64 tokens, wave 0), adjust row + Z ----
  double dz = 0.0;
  if (tid < NT && first) {
    const float e_old = expf(x_tk - M);
    const float e_new = expf(x_tk - (fpen * (float)cnt + ppen) * invT - M);
    dz = (double)e_new - (double)e_old;
    row[tk] = e_new;
  }
  if (wav == 0) {
#pragma unroll
    for (int o = 32; o; o >>= 1) dz += __shfl_down(dz, o);
    if (lane == 0) s_dz = dz;
  }
  __syncthreads();
  Z += s_dz;
  const float invZ = (float)(1.0 / Z);

  // ---- Pass B: p = e*invZ, histogram (count + fp32 sum per bin), nonzero count ----
  int nz_l = 0;
  for (int i = tid * 4; i < NV; i += TPB * 4) {
    float4 e4 = *(const float4*)(row + i);
    float4 p4;
    p4.x = e4.x * invZ; p4.y = e4.y * invZ; p4.z = e4.z * invZ; p4.w = e4.w * invZ;
    *(float4*)(row + i) = p4;
    unsigned k;
    k = __float_as_uint(p4.x); if (k) { nz_l++; atomicAdd(&hcnt[k >> BSHIFT], 1); atomicAdd(&hsum[k >> BSHIFT], p4.x); }
    k = __float_as_uint(p4.y); if (k) { nz_l++; atomicAdd(&hcnt[k >> BSHIFT], 1); atomicAdd(&hsum[k >> BSHIFT], p4.y); }
    k = __float_as_uint(p4.z); if (k) { nz_l++; atomicAdd(&hcnt[k >> BSHIFT], 1); atomicAdd(&hsum[k >> BSHIFT], p4.z); }
    k = __float_as_uint(p4.w); if (k) { nz_l++; atomicAdd(&hcnt[k >> BSHIFT], 1); atomicAdd(&hsum[k >> BSHIFT], p4.w); }
  }
#pragma unroll
  for (int o = 32; o; o >>= 1) nz_l += __shfl_down(nz_l, o);
  if (lane == 0) s_i[wav] = nz_l;
  __syncthreads();
  int NZ = 0;
#pragma unroll
  for (int w = 0; w < NWAVE; w++) NZ += s_i[w];

  // ---- suffix scan over bins: C_gt[b], S_gt[b] = count/sum of keys in bins > b ----
  const int b0 = tid * BPT;
  const int    c0b = hcnt[b0], c1b = hcnt[b0 + 1];
  const double sm0 = (double)hsum[b0], sm1 = (double)hsum[b0 + 1];
  sc_c[tid] = c0b + c1b; sc_s[tid] = sm0 + sm1;
  __syncthreads();
  for (int off = 1; off < TPB; off <<= 1) {
    int cv = sc_c[tid]; double sv = sc_s[tid];
    int cn = 0; double sn = 0.0;
    if (tid + off < TPB) { cn = sc_c[tid + off]; sn = sc_s[tid + off]; }
    __syncthreads();
    sc_c[tid] = cv + cn; sc_s[tid] = sv + sn;
    __syncthreads();
  }
  const int    exc_c = (tid < TPB - 1) ? sc_c[tid + 1] : 0;
  const double exc_s = (tid < TPB - 1) ? sc_s[tid + 1] : 0.0;
  hcnt[b0 + 1] = exc_c;        hsumd[b0 + 1] = exc_s;
  hcnt[b0]     = exc_c + c1b;  hsumd[b0]     = exc_s + sm1;
  __syncthreads();

  // ---- locate cutoff bin b*: A(b) = (C_gt < ktop && S_gt <= topp), monotone in b ----
  {
    const bool A1 = (hcnt[b0] < ktop) && (hsumd[b0] <= topp);
    const bool A2 = (hcnt[b0 + 1] < ktop) && (hsumd[b0 + 1] <= topp);
    bool Ap = false;
    if (b0 > 0) Ap = (hcnt[b0 - 1] < ktop) && (hsumd[b0 - 1] <= topp);
    if (A1 && !Ap) s_bstar = b0;
    if (A2 && !A1) s_bstar = b0 + 1;
  }
  __syncthreads();
  const int bs = s_bstar;

  unsigned hi = (((unsigned)(bs + 1)) << BSHIFT) - 1u;
  unsigned lo;
  int Chi = hcnt[bs]; double Shi = hsumd[bs];
  int Clo; double Slo;
  const int    ChiBin = Chi;
  const double ShiBin = Shi;
  if (bs > 0) { lo = (((unsigned)bs) << BSHIFT) - 1u; Clo = hcnt[bs - 1]; Slo = hsumd[bs - 1]; }
  else        { lo = 0u; Clo = NZ; Slo = Z; }
  (void)Slo;

  // ---- collect candidates: elements with key in (lo, hi] ----
  for (int i = tid * 4; i < NV; i += TPB * 4) {
    float4 p4 = *(const float4*)(row + i);
    unsigned k;
    k = __float_as_uint(p4.x); if (k > lo && k <= hi) { int j = atomicAdd(&s_ncand, 1); if (j < CAP) { cand_key[j] = k; cand_idx[j] = i; } }
    k = __float_as_uint(p4.y); if (k > lo && k <= hi) { int j = atomicAdd(&s_ncand, 1); if (j < CAP) { cand_key[j] = k; cand_idx[j] = i + 1; } }
    k = __float_as_uint(p4.z); if (k > lo && k <= hi) { int j = atomicAdd(&s_ncand, 1); if (j < CAP) { cand_key[j] = k; cand_idx[j] = i + 2; } }
    k = __float_as_uint(p4.w); if (k > lo && k <= hi) { int j = atomicAdd(&s_ncand, 1); if (j < CAP) { cand_key[j] = k; cand_idx[j] = i + 3; } }
  }
  __syncthreads();
  const int ncand = s_ncand;
  const bool use_cand = (ncand <= CAP);

  // ---- bisection for exact cutoff u* within (lo, hi] (<=5 iters, span 2^19) ----
  while (hi - lo > 1u) {
    const unsigned step = ((hi - lo) + 15u) >> 4;
    unsigned u[15];
#pragma unroll
    for (int i = 0; i < 15; i++) {
      unsigned ui = lo + (unsigned)(i + 1) * step;
      u[i] = (ui > hi) ? hi : ui;
    }
    int cnt15[15]; double sm15[15];
#pragma unroll
    for (int i = 0; i < 15; i++) { cnt15[i] = 0; sm15[i] = 0.0; }
    if (use_cand) {
      for (int j = tid; j < ncand; j += TPB) {
        const unsigned k = cand_key[j];
        const double p = (double)__uint_as_float(k);
#pragma unroll
        for (int i = 0; i < 15; i++)
          if (k > u[i]) { cnt15[i]++; sm15[i] += p; }
      }
    } else {
      for (int v = tid; v < NV; v += TPB) {
        const float pf = row[v];
        const unsigned k = __float_as_uint(pf);
#pragma unroll
        for (int i = 0; i < 15; i++)
          if (k > u[i]) { cnt15[i]++; sm15[i] += (double)pf; }
      }
    }
    __syncthreads();
#pragma unroll
    for (int i = 0; i < 15; i++) {
      int c = cnt15[i]; double sv = sm15[i];
#pragma unroll
      for (int o = 32; o; o >>= 1) { c += __shfl_down(c, o); sv += __shfl_down(sv, o); }
      if (lane == 0) { s_c[wav][i] = c; s_s[wav][i] = sv; }
    }
    __syncthreads();
    if (tid < 15) {
      int c = 0; double sv = 0.0;
#pragma unroll
      for (int w = 0; w < NWAVE; w++) { c += s_c[w][tid]; sv += s_s[w][tid]; }
      s_tc[tid] = c; s_ts[tid] = sv;
    }
    __syncthreads();
    const int    base_c = use_cand ? ChiBin : 0;
    const double base_s = use_cand ? ShiBin : 0.0;
    for (int i = 0; i < 15; i++) {
      const int c = base_c + s_tc[i];
      const double sv = base_s + s_ts[i];
      const bool At = (c < ktop) && (sv <= topp);
      if (At) { Chi = c; Shi = sv; hi = u[i]; break; }
      if (u[i] < hi) { lo = u[i]; Clo = c; }
    }
  }

  // ---- cutoff resolved: u* = hi ----
  const unsigned ustar = hi;
  const int c_eq = Clo - Chi;
  int m = c_eq;
  {
    const int lim = ktop - Chi;
    if (lim < m) m = lim;
    const double tcut = (double)__uint_as_float(ustar);
    double rem = topp - Shi;
    if (rem < 0.0) rem = 0.0;
    const double Rd = floor(rem / tcut) + 1.0;
    if (Rd < (double)m) m = (int)Rd;
  }
  if (m < 1) m = 1;

  if (m == c_eq) {
    for (int i = tid * 4; i < NV; i += TPB * 4) {
      float4 p4 = *(const float4*)(row + i);
      p4.x = (__float_as_uint(p4.x) >= ustar) ? p4.x : 0.f;
      p4.y = (__float_as_uint(p4.y) >= ustar) ? p4.y : 0.f;
      p4.z = (__float_as_uint(p4.z) >= ustar) ? p4.z : 0.f;
      p4.w = (__float_as_uint(p4.w) >= ustar) ? p4.w : 0.f;
      *(float4*)(row + i) = p4;
    }
  } else {
    // rare tie path: index-ordered ranking over per-thread contiguous chunks
    const int CH = (NV + TPB - 1) / TPB;
    int base = tid * CH; if (base > NV) base = NV;
    int end = base + CH; if (end > NV) end = NV;
    int myc = 0;
    for (int v = base; v < end; v++) myc += (__float_as_uint(row[v]) == ustar);
    s_rank[tid] = myc;
    __syncthreads();
    for (int off = 1; off < TPB; off <<= 1) {
      int v = s_rank[tid];
      int vn = (tid >= off) ? s_rank[tid - off] : 0;
      __syncthreads();
      s_rank[tid] = v + vn;
      __syncthreads();
    }
    int r = (tid > 0) ? s_rank[tid - 1] : 0;
    for (int v = base; v < end; v++) {
      const float p = row[v];
      const unsigned key = __float_as_uint(p);
      bool kept;
      if (key > ustar) kept = true;
      else if (key == ustar) { kept = (r < m); r++; }
      else kept = false;
      row[v] = kept ? p : 0.0f;
    }
  }
}

extern "C" void kernel_launch(void* const* d_in, const int* in_sizes, int n_in,
                              void* d_out, int out_size, void* d_ws, size_t ws_size,
                              hipStream_t stream) {
  (void)in_sizes; (void)n_in; (void)out_size; (void)ws_size;
  const float* hidden = (const float*)d_in[0];
  const float* emb    = (const float*)d_in[1];
  const int*   toks   = (const int*)d_in[2];
  const float* pres   = (const float*)d_in[3];
  const float* freq   = (const float*)d_in[4];
  const float* temp   = (const float*)d_in[5];
  const float* topp   = (const float*)d_in[6];
  const int*   topk   = (const int*)d_in[7];
  float* out = (float*)d_out;
  unsigned* ws_max = (unsigned*)d_ws;

  hipMemsetAsync(ws_max, 0, NB * sizeof(unsigned), stream);
  dim3 ggrid(NV / 128, NB / 128);
  gemm_f32<<<ggrid, 256, 0, stream>>>(hidden, emb, temp, ws_max, out);
  sample_rows<<<NB, TPB, 0, stream>>>(toks, pres, freq, temp, topp, topk, ws_max, out);
}

// Round 3
// 545.238 us; speedup vs baseline: 1.3584x; 1.2430x over previous
//
#include <hip/hip_runtime.h>
#include <math.h>

#define NB 256
#define NV 32000
#define ND 1024
#define NT 64
#define TPB 1024
#define NWAVE (TPB / 64)   // 16
#define NBINS 2048
#define BSHIFT 19
#define BPT (NBINS / TPB)  // 2
#define CAP 1024

// GEMM config: tile M=256 x N=64, BK=16 fp32 k per iter (48 f16: 16 accA + 32 accB)
#define GN 64
#define ASTR 56            // padded row stride (f16) for A lds tile
#define BSTR 56
#define NKB 64             // 1024/16 k-blocks
#define ASLAB (256 * ASTR) // f16 per k-block slab = 14336 (28672 B)
#define NGBLK (NV / GN)    // 500
#define INV2048F 4.8828125e-4f

typedef _Float16 f16x8 __attribute__((ext_vector_type(8)));
typedef _Float16 f16x4 __attribute__((ext_vector_type(4)));
typedef float f32x16 __attribute__((ext_vector_type(16)));
typedef __attribute__((address_space(3))) void lds_void;
typedef __attribute__((address_space(1))) void glb_void;

__device__ __forceinline__ unsigned mono_enc(float f) {
  unsigned u = __float_as_uint(f);
  return (u & 0x80000000u) ? ~u : (u | 0x80000000u);
}
__device__ __forceinline__ float mono_dec(unsigned u) {
  return (u & 0x80000000u) ? __uint_as_float(u & 0x7FFFFFFFu) : __uint_as_float(~u);
}

// ---------------- convert A (hidden) into split-f16 K-blocked slabs in ws ----------------
// slab kb: [256 m][ASTR]: slots 0..15 = ah(kk), 16+2kk = ah, 17+2kk = al*2^11
__global__ __launch_bounds__(256) void convert_A(const float* __restrict__ hidden,
                                                 _Float16* __restrict__ A3) {
  const int g = blockIdx.x * 256 + threadIdx.x;  // 262144 total
  const int m = g >> 10, k = g & 1023;
  const float a = hidden[g];
  const _Float16 ah = (_Float16)a;
  const float r = a - (float)ah;
  const _Float16 al2 = (_Float16)(r * 2048.0f);
  const int kb = k >> 4, kk = k & 15;
  _Float16* base = A3 + (size_t)(kb * 256 + m) * ASTR;
  base[kk] = ah;
  base[16 + 2 * kk] = ah;
  base[17 + 2 * kk] = al2;
}

// ---------------- MFMA f16-split GEMM: x = (hidden·emb^T)*invT, per-block rowmax ----------
__global__ __launch_bounds__(256, 2) void gemm_f16s(
    const float* __restrict__ Bm,      // embedding [32000][1024] fp32
    const _Float16* __restrict__ A3,   // ws slabs
    const float* __restrict__ temp,    // [256]
    unsigned* __restrict__ pmax,       // [NGBLK][256] mono-enc row max
    float* __restrict__ C)             // x  [256][32000]
{
  __shared__ _Float16 Als[ASLAB];      // 28672 B
  __shared__ _Float16 Bls[GN * BSTR];  // 7168 B
  __shared__ float s_invT[256];
  __shared__ unsigned s_pm[256];

  const int t = threadIdx.x;
  const int l = t & 63, w = t >> 6;
  const int n0 = blockIdx.x * GN;
  s_invT[t] = 1.0f / temp[t];
  s_pm[t] = 0u;

  f32x16 accA[2][2] = {};
  f32x16 accB[2][2] = {};

  const int bn = t >> 2, bk4 = (t & 3) * 4;          // B staging map
  const int l31 = l & 31, lh = l >> 5;
  const int ka = lh * 8;
  const int mb = w * 64;

  for (int kb = 0; kb < NKB; kb++) {
    // A: async global->LDS, 7 issues per thread-wave-slot
    {
      const char* ga = (const char*)A3 + (size_t)kb * (ASLAB * 2) + (w * 7) * 1024 + l * 16;
      char* la = (char*)Als + (w * 7) * 1024;
#pragma unroll
      for (int i = 0; i < 7; i++)
        __builtin_amdgcn_global_load_lds((const glb_void*)(ga + i * 1024),
                                         (lds_void*)(la + i * 1024), 16, 0, 0);
    }
    // B: coalesced fp32 load + split-convert + LDS write
    {
      const float4 bv = *(const float4*)(Bm + (size_t)(n0 + bn) * ND + kb * 16 + bk4);
      const _Float16 h0 = (_Float16)bv.x, h1 = (_Float16)bv.y,
                     h2 = (_Float16)bv.z, h3 = (_Float16)bv.w;
      const _Float16 l0 = (_Float16)((bv.x - (float)h0) * 2048.0f);
      const _Float16 l1 = (_Float16)((bv.y - (float)h1) * 2048.0f);
      const _Float16 l2 = (_Float16)((bv.z - (float)h2) * 2048.0f);
      const _Float16 l3 = (_Float16)((bv.w - (float)h3) * 2048.0f);
      _Float16* prow = Bls + bn * BSTR;
      *(f16x4*)(prow + bk4) = (f16x4){h0, h1, h2, h3};
      *(f16x8*)(prow + 16 + 2 * bk4) = (f16x8){l0, h0, l1, h1, l2, h2, l3, h3};
    }
    __syncthreads();
    // compute: accA (k 0..15), accB (k 16..47)
    {
      const _Float16* Ap = Als + (size_t)(mb + l31) * ASTR + ka;
      const _Float16* Bp = Bls + (size_t)l31 * BSTR + ka;
      f16x8 a0 = *(const f16x8*)(Ap);
      f16x8 a1 = *(const f16x8*)(Ap + 32 * ASTR);
      f16x8 b0 = *(const f16x8*)(Bp);
      f16x8 b1 = *(const f16x8*)(Bp + 32 * BSTR);
      accA[0][0] = __builtin_amdgcn_mfma_f32_32x32x16_f16(a0, b0, accA[0][0], 0, 0, 0);
      accA[0][1] = __builtin_amdgcn_mfma_f32_32x32x16_f16(a0, b1, accA[0][1], 0, 0, 0);
      accA[1][0] = __builtin_amdgcn_mfma_f32_32x32x16_f16(a1, b0, accA[1][0], 0, 0, 0);
      accA[1][1] = __builtin_amdgcn_mfma_f32_32x32x16_f16(a1, b1, accA[1][1], 0, 0, 0);
#pragma unroll
      for (int s = 0; s < 2; s++) {
        const int off = 16 + s * 16;
        f16x8 c0 = *(const f16x8*)(Ap + off);
        f16x8 c1 = *(const f16x8*)(Ap + 32 * ASTR + off);
        f16x8 d0 = *(const f16x8*)(Bp + off);
        f16x8 d1 = *(const f16x8*)(Bp + 32 * BSTR + off);
        accB[0][0] = __builtin_amdgcn_mfma_f32_32x32x16_f16(c0, d0, accB[0][0], 0, 0, 0);
        accB[0][1] = __builtin_amdgcn_mfma_f32_32x32x16_f16(c0, d1, accB[0][1], 0, 0, 0);
        accB[1][0] = __builtin_amdgcn_mfma_f32_32x32x16_f16(c1, d0, accB[1][0], 0, 0, 0);
        accB[1][1] = __builtin_amdgcn_mfma_f32_32x32x16_f16(c1, d1, accB[1][1], 0, 0, 0);
      }
    }
    __syncthreads();
  }

  // epilogue: combine, scale by invT, store, per-block row max
#pragma unroll
  for (int mi = 0; mi < 2; mi++) {
#pragma unroll
    for (int r = 0; r < 16; r++) {
      const int row = mb + mi * 32 + (r & 3) + 8 * (r >> 2) + 4 * lh;
      const float it = s_invT[row];
      float v0 = (accA[mi][0][r] + accB[mi][0][r] * INV2048F) * it;
      float v1 = (accA[mi][1][r] + accB[mi][1][r] * INV2048F) * it;
      C[(size_t)row * NV + n0 + l31] = v0;
      C[(size_t)row * NV + n0 + 32 + l31] = v1;
      float mx = fmaxf(v0, v1);
#pragma unroll
      for (int o = 1; o < 32; o <<= 1) mx = fmaxf(mx, __shfl_xor(mx, o));
      if (l31 == 0) atomicMax(&s_pm[row], mono_enc(mx));
    }
  }
  __syncthreads();
  pmax[(size_t)blockIdx.x * 256 + t] = s_pm[t];
}

// ---------------- per-row: exp/Z/hist -> cutoff (e-space) -> fused filter+collect ----------
__global__ __launch_bounds__(TPB) void sample_rows(
    const int* __restrict__ toks, const float* __restrict__ pres,
    const float* __restrict__ freq, const float* __restrict__ temp,
    const float* __restrict__ topp_a, const int* __restrict__ topk_a,
    const unsigned* __restrict__ pmax, float* __restrict__ buf)
{
  const int b = blockIdx.x, tid = threadIdx.x;
  const int lane = tid & 63, wav = tid >> 6;
  float* row = buf + (size_t)b * NV;

  __shared__ int      s_tok[NT];
  __shared__ double   s_d[NWAVE];
  __shared__ int      s_i[NWAVE];
  __shared__ unsigned s_u[NWAVE];
  __shared__ int      hcnt[NBINS];
  __shared__ float    hsum[NBINS];
  __shared__ double   hsumd[NBINS];
  __shared__ int      sc_c[TPB];
  __shared__ double   sc_s[TPB];
  __shared__ int      s_c[NWAVE][16];
  __shared__ double   s_s[NWAVE][16];
  __shared__ int      s_tc[16];
  __shared__ double   s_ts[16];
  __shared__ unsigned cand_key[CAP];
  __shared__ int      cand_idx[CAP];
  __shared__ int      s_rank[TPB];
  __shared__ int      s_ncand;
  __shared__ int      s_bstar;
  __shared__ int      s_dnz;
  __shared__ double   s_dz;

  const float  invT = 1.0f / temp[b];
  const float  fpen = freq[b], ppen = pres[b];
  const double topp = (double)topp_a[b];
  const int    ktop = topk_a[b];

  // row max from GEMM per-block partials
  unsigned um = 0u;
  for (int i = tid; i < NGBLK; i += TPB) um = max(um, pmax[(size_t)i * 256 + b]);
#pragma unroll
  for (int o = 32; o; o >>= 1) um = max(um, (unsigned)__shfl_down(um, o));
  if (lane == 0) s_u[wav] = um;

  if (tid < NT) s_tok[tid] = toks[b * NT + tid];
  for (int i = tid; i < NBINS; i += TPB) { hcnt[i] = 0; hsum[i] = 0.f; }
  if (tid == 0) { s_ncand = 0; s_bstar = 0; s_dnz = 0; }
  __syncthreads();
  um = s_u[0];
#pragma unroll
  for (int w2 = 1; w2 < NWAVE; w2++) um = max(um, s_u[w2]);
  const float M = mono_dec(um);

  // token multiplicity + first-occurrence; snapshot x_tk before overwrite
  float x_tk = 0.f; int cnt = 0; bool first = false; int tk = -1;
  if (tid < NT) {
    tk = s_tok[tid];
    first = true;
    for (int j = 0; j < NT; j++)
      if (s_tok[j] == tk) { if (j < tid) first = false; cnt++; }
    x_tk = row[tk];
  }
  __syncthreads();

  // ---- Pass A: e = exp(x - M), Z, nonzero count, e-key histogram ----
  double zl = 0.0; int nz_l = 0;
  for (int i = tid * 4; i < NV; i += TPB * 4) {
    float4 x4 = *(const float4*)(row + i);
    float4 e4;
    e4.x = expf(x4.x - M); e4.y = expf(x4.y - M);
    e4.z = expf(x4.z - M); e4.w = expf(x4.w - M);
    *(float4*)(row + i) = e4;
    zl += (double)e4.x + (double)e4.y + (double)e4.z + (double)e4.w;
    unsigned k;
    k = __float_as_uint(e4.x); if (k) { nz_l++; atomicAdd(&hcnt[k >> BSHIFT], 1); atomicAdd(&hsum[k >> BSHIFT], e4.x); }
    k = __float_as_uint(e4.y); if (k) { nz_l++; atomicAdd(&hcnt[k >> BSHIFT], 1); atomicAdd(&hsum[k >> BSHIFT], e4.y); }
    k = __float_as_uint(e4.z); if (k) { nz_l++; atomicAdd(&hcnt[k >> BSHIFT], 1); atomicAdd(&hsum[k >> BSHIFT], e4.z); }
    k = __float_as_uint(e4.w); if (k) { nz_l++; atomicAdd(&hcnt[k >> BSHIFT], 1); atomicAdd(&hsum[k >> BSHIFT], e4.w); }
  }
#pragma unroll
  for (int o = 32; o; o >>= 1) { zl += __shfl_down(zl, o); nz_l += __shfl_down(nz_l, o); }
  if (lane == 0) { s_d[wav] = zl; s_i[wav] = nz_l; }
  __syncthreads();
  double Z = 0.0; int NZ = 0;
#pragma unroll
  for (int w2 = 0; w2 < NWAVE; w2++) { Z += s_d[w2]; NZ += s_i[w2]; }

  // ---- penalty fixup: adjust row, Z, NZ, histogram ----
  double dz = 0.0;
  if (tid < NT && first) {
    const float e_old = expf(x_tk - M);
    const float e_new = expf(x_tk - (fpen * (float)cnt + ppen) * invT - M);
    dz = (double)e_new - (double)e_old;
    row[tk] = e_new;
    const unsigned ko = __float_as_uint(e_old), kn = __float_as_uint(e_new);
    int dn = 0;
    if (ko) { atomicSub(&hcnt[ko >> BSHIFT], 1); atomicAdd(&hsum[ko >> BSHIFT], -e_old); dn--; }
    if (kn) { atomicAdd(&hcnt[kn >> BSHIFT], 1); atomicAdd(&hsum[kn >> BSHIFT], e_new); dn++; }
    if (dn) atomicAdd(&s_dnz, dn);
  }
  if (wav == 0) {
#pragma unroll
    for (int o = 32; o; o >>= 1) dz += __shfl_down(dz, o);
    if (lane == 0) s_dz = dz;
  }
  __syncthreads();
  Z += s_dz; NZ += s_dnz;
  const float  invZ  = (float)(1.0 / Z);
  const double toppZ = topp * Z;

  // ---- suffix scan over bins: C_gt, S_gt ----
  const int b0 = tid * BPT;
  const int    c0b = hcnt[b0], c1b = hcnt[b0 + 1];
  const double sm0 = (double)hsum[b0], sm1 = (double)hsum[b0 + 1];
  __syncthreads();
  sc_c[tid] = c0b + c1b; sc_s[tid] = sm0 + sm1;
  __syncthreads();
  for (int off = 1; off < TPB; off <<= 1) {
    int cv = sc_c[tid]; double sv = sc_s[tid];
    int cn = 0; double sn = 0.0;
    if (tid + off < TPB) { cn = sc_c[tid + off]; sn = sc_s[tid + off]; }
    __syncthreads();
    sc_c[tid] = cv + cn; sc_s[tid] = sv + sn;
    __syncthreads();
  }
  const int    exc_c = (tid < TPB - 1) ? sc_c[tid + 1] : 0;
  const double exc_s = (tid < TPB - 1) ? sc_s[tid + 1] : 0.0;
  hcnt[b0 + 1] = exc_c;        hsumd[b0 + 1] = exc_s;
  hcnt[b0]     = exc_c + c1b;  hsumd[b0]     = exc_s + sm1;
  __syncthreads();

  // ---- locate cutoff bin b*: A(b) = (C_gt < ktop && S_gt <= toppZ) ----
  {
    const bool A1 = (hcnt[b0] < ktop) && (hsumd[b0] <= toppZ);
    const bool A2 = (hcnt[b0 + 1] < ktop) && (hsumd[b0 + 1] <= toppZ);
    bool Ap = false;
    if (b0 > 0) Ap = (hcnt[b0 - 1] < ktop) && (hsumd[b0 - 1] <= toppZ);
    if (A1 && !Ap) s_bstar = b0;
    if (A2 && !A1) s_bstar = b0 + 1;
  }
  __syncthreads();
  const int bs = s_bstar;

  const unsigned hiKey = (((unsigned)(bs + 1)) << BSHIFT) - 1u;
  const unsigned loKey = (bs > 0) ? ((((unsigned)bs) << BSHIFT) - 1u) : 0u;
  const int    ChiBin = hcnt[bs];
  const double ShiBin = hsumd[bs];
  const int    CloBin = (bs > 0) ? hcnt[bs - 1] : NZ;
  const int    c_in   = CloBin - ChiBin;

  unsigned ustar; int ChiF, c_eq; double ShiF;

  if (c_in <= CAP) {
    // ---- Pass B (fused): write definite keep/zero; collect in-bin candidates ----
    for (int i = tid * 4; i < NV; i += TPB * 4) {
      float4 e4 = *(const float4*)(row + i);
      float4 o4;
      unsigned k;
      k = __float_as_uint(e4.x);
      o4.x = (k > hiKey) ? e4.x * invZ : 0.f;
      if (k > loKey && k <= hiKey) { int j = atomicAdd(&s_ncand, 1); cand_key[j] = k; cand_idx[j] = i; }
      k = __float_as_uint(e4.y);
      o4.y = (k > hiKey) ? e4.y * invZ : 0.f;
      if (k > loKey && k <= hiKey) { int j = atomicAdd(&s_ncand, 1); cand_key[j] = k; cand_idx[j] = i + 1; }
      k = __float_as_uint(e4.z);
      o4.z = (k > hiKey) ? e4.z * invZ : 0.f;
      if (k > loKey && k <= hiKey) { int j = atomicAdd(&s_ncand, 1); cand_key[j] = k; cand_idx[j] = i + 2; }
      k = __float_as_uint(e4.w);
      o4.w = (k > hiKey) ? e4.w * invZ : 0.f;
      if (k > loKey && k <= hiKey) { int j = atomicAdd(&s_ncand, 1); cand_key[j] = k; cand_idx[j] = i + 3; }
      *(float4*)(row + i) = o4;
    }
    __syncthreads();
    const int ncand = s_ncand;

    // ---- bisection on candidate list (e-space) ----
    unsigned lo_ = loKey, hi_ = hiKey;
    int Chi = ChiBin, Clo = CloBin;
    double Shi = ShiBin;
    while (hi_ - lo_ > 1u) {
      const unsigned step = ((hi_ - lo_) + 15u) >> 4;
      unsigned u[15];
#pragma unroll
      for (int i = 0; i < 15; i++) {
        unsigned ui = lo_ + (unsigned)(i + 1) * step;
        u[i] = (ui > hi_) ? hi_ : ui;
      }
      int cnt15[15]; double sm15[15];
#pragma unroll
      for (int i = 0; i < 15; i++) { cnt15[i] = 0; sm15[i] = 0.0; }
      for (int j = tid; j < ncand; j += TPB) {
        const unsigned k = cand_key[j];
        const double p = (double)__uint_as_float(k);
#pragma unroll
        for (int i = 0; i < 15; i++)
          if (k > u[i]) { cnt15[i]++; sm15[i] += p; }
      }
      __syncthreads();
#pragma unroll
      for (int i = 0; i < 15; i++) {
        int c = cnt15[i]; double sv = sm15[i];
#pragma unroll
        for (int o = 32; o; o >>= 1) { c += __shfl_down(c, o); sv += __shfl_down(sv, o); }
        if (lane == 0) { s_c[wav][i] = c; s_s[wav][i] = sv; }
      }
      __syncthreads();
      if (tid < 15) {
        int c = 0; double sv = 0.0;
#pragma unroll
        for (int w2 = 0; w2 < NWAVE; w2++) { c += s_c[w2][tid]; sv += s_s[w2][tid]; }
        s_tc[tid] = c; s_ts[tid] = sv;
      }
      __syncthreads();
      for (int i = 0; i < 15; i++) {
        const int c = ChiBin + s_tc[i];
        const double sv = ShiBin + s_ts[i];
        const bool At = (c < ktop) && (sv <= toppZ);
        if (At) { Chi = c; Shi = sv; hi_ = u[i]; break; }
        if (u[i] < hi_) { lo_ = u[i]; Clo = c; }
      }
    }
    ustar = hi_; ChiF = Chi; ShiF = Shi; c_eq = Clo - Chi;

    int m = c_eq;
    {
      const int lim = ktop - ChiF;
      if (lim < m) m = lim;
      const double tcut = (double)__uint_as_float(ustar);
      double rem = toppZ - ShiF;
      if (rem < 0.0) rem = 0.0;
      const double Rd = floor(rem / tcut) + 1.0;
      if (Rd < (double)m) m = (int)Rd;
    }
    if (m < 1) m = 1;

    // ---- scatter kept candidates (index-ordered tie ranks) ----
    for (int j = tid; j < ncand; j += TPB) {
      const unsigned k = cand_key[j];
      bool kept = false;
      if (k > ustar) kept = true;
      else if (k == ustar) {
        int r = 0;
        for (int i2 = 0; i2 < ncand; i2++)
          r += (cand_key[i2] == ustar && cand_idx[i2] < cand_idx[j]);
        kept = (r < m);
      }
      if (kept) row[cand_idx[j]] = __uint_as_float(k) * invZ;
    }
  } else {
    // ---- fallback: full-row bisection + full filter (rare) ----
    unsigned lo_ = loKey, hi_ = hiKey;
    int Chi = ChiBin, Clo = CloBin;
    double Shi = ShiBin;
    while (hi_ - lo_ > 1u) {
      const unsigned step = ((hi_ - lo_) + 15u) >> 4;
      unsigned u[15];
#pragma unroll
      for (int i = 0; i < 15; i++) {
        unsigned ui = lo_ + (unsigned)(i + 1) * step;
        u[i] = (ui > hi_) ? hi_ : ui;
      }
      int cnt15[15]; double sm15[15];
#pragma unroll
      for (int i = 0; i < 15; i++) { cnt15[i] = 0; sm15[i] = 0.0; }
      for (int v = tid; v < NV; v += TPB) {
        const float ef = row[v];
        const unsigned k = __float_as_uint(ef);
#pragma unroll
        for (int i = 0; i < 15; i++)
          if (k > u[i]) { cnt15[i]++; sm15[i] += (double)ef; }
      }
      __syncthreads();
#pragma unroll
      for (int i = 0; i < 15; i++) {
        int c = cnt15[i]; double sv = sm15[i];
#pragma unroll
        for (int o = 32; o; o >>= 1) { c += __shfl_down(c, o); sv += __shfl_down(sv, o); }
        if (lane == 0) { s_c[wav][i] = c; s_s[wav][i] = sv; }
      }
      __syncthreads();
      if (tid < 15) {
        int c = 0; double sv = 0.0;
#pragma unroll
        for (int w2 = 0; w2 < NWAVE; w2++) { c += s_c[w2][tid]; sv += s_s[w2][tid]; }
        s_tc[tid] = c; s_ts[tid] = sv;
      }
      __syncthreads();
      for (int i = 0; i < 15; i++) {
        const int c = s_tc[i];
        const double sv = s_ts[i];
        const bool At = (c < ktop) && (sv <= toppZ);
        if (At) { Chi = c; Shi = sv; hi_ = u[i]; break; }
        if (u[i] < hi_) { lo_ = u[i]; Clo = c; }
      }
    }
    ustar = hi_; ChiF = Chi; ShiF = Shi; c_eq = Clo - Chi;

    int m = c_eq;
    {
      const int lim = ktop - ChiF;
      if (lim < m) m = lim;
      const double tcut = (double)__uint_as_float(ustar);
      double rem = toppZ - ShiF;
      if (rem < 0.0) rem = 0.0;
      const double Rd = floor(rem / tcut) + 1.0;
      if (Rd < (double)m) m = (int)Rd;
    }
    if (m < 1) m = 1;

    const int CH = (NV + TPB - 1) / TPB;
    int base = tid * CH; if (base > NV) base = NV;
    int end = base + CH; if (end > NV) end = NV;
    int myc = 0;
    for (int v = base; v < end; v++) myc += (__float_as_uint(row[v]) == ustar);
    s_rank[tid] = myc;
    __syncthreads();
    for (int off = 1; off < TPB; off <<= 1) {
      int v = s_rank[tid];
      int vn = (tid >= off) ? s_rank[tid - off] : 0;
      __syncthreads();
      s_rank[tid] = v + vn;
      __syncthreads();
    }
    int r = (tid > 0) ? s_rank[tid - 1] : 0;
    for (int v = base; v < end; v++) {
      const float ef = row[v];
      const unsigned key = __float_as_uint(ef);
      bool kept;
      if (key > ustar) kept = true;
      else if (key == ustar) { kept = (r < m); r++; }
      else kept = false;
      row[v] = kept ? ef * invZ : 0.0f;
    }
  }
}

extern "C" void kernel_launch(void* const* d_in, const int* in_sizes, int n_in,
                              void* d_out, int out_size, void* d_ws, size_t ws_size,
                              hipStream_t stream) {
  (void)in_sizes; (void)n_in; (void)out_size; (void)ws_size;
  const float* hidden = (const float*)d_in[0];
  const float* emb    = (const float*)d_in[1];
  const int*   toks   = (const int*)d_in[2];
  const float* pres   = (const float*)d_in[3];
  const float* freq   = (const float*)d_in[4];
  const float* temp   = (const float*)d_in[5];
  const float* topp   = (const float*)d_in[6];
  const int*   topk   = (const int*)d_in[7];
  float* out = (float*)d_out;

  _Float16* A3   = (_Float16*)d_ws;                              // 64*28672 B = 1.835 MB
  unsigned* pmax = (unsigned*)((char*)d_ws + (size_t)NKB * ASLAB * 2);  // 500*256*4 B

  convert_A<<<1024, 256, 0, stream>>>(hidden, A3);
  gemm_f16s<<<NGBLK, 256, 0, stream>>>(emb, A3, temp, pmax, out);
  sample_rows<<<NB, TPB, 0, stream>>>(toks, pres, freq, temp, topp, topk, pmax, out);
}